// Round 1
// 161.362 us; speedup vs baseline: 1.0108x; 1.0108x over previous
//
#include <hip/hip_runtime.h>
#include <hip/hip_bf16.h>
#include <math.h>

// R9: 3 dispatches.
//  K1 prep_xt_k  : weights->bf16 transpose + x NCHW -> xT[pix][c]
//  K2 stage2_gi_k: blocks 0-255 = dwconv+LN+GELU+OM-GEMM (XCD-swizzled rows);
//                  blocks 256-511 = input-proj GEMM (4x 64x64 sub-tiles/block)
//  K3 fused_so_k : deformable sampling -> LDS tile -> output-proj GEMM -> fp32 NCHW
// samp intermediate eliminated (16.8 MB HBM round trip removed).

using bf16x8 = __attribute__((ext_vector_type(8))) short;
using f32x4  = __attribute__((ext_vector_type(4))) float;

#define GLOBAL_AS __attribute__((address_space(1)))
#define LDS_AS    __attribute__((address_space(3)))

static __device__ inline void g2lds16(const void* g, void* l) {
  __builtin_amdgcn_global_load_lds((const GLOBAL_AS int*)g, (LDS_AS int*)l, 16, 0, 0);
}
static __device__ inline unsigned short f2bf(float v) {
  __hip_bfloat16 b = __float2bfloat16(v);
  return *reinterpret_cast<unsigned short*>(&b);
}
static __device__ inline float us2f(unsigned short u) {
  union { unsigned u; float f; } c; c.u = ((unsigned)u) << 16; return c.f;
}

// ---------------- prep (weights transpose->bf16) + x NCHW -> xT [pix][c] ----
__global__ __launch_bounds__(256) void prep_xt_k(
    const float* __restrict__ x,
    const float* __restrict__ inp_w, const float* __restrict__ off_w,
    const float* __restrict__ off_b, const float* __restrict__ mask_w,
    const float* __restrict__ mask_b, const float* __restrict__ out_w,
    __hip_bfloat16* __restrict__ BtI, __hip_bfloat16* __restrict__ BtOM,
    __hip_bfloat16* __restrict__ BtO, float* __restrict__ bOM,
    __hip_bfloat16* __restrict__ xT)
{
  __shared__ float tile[32][65];
  const int b = blockIdx.x, t = threadIdx.x;
  if (b < 1024) {
    if (b < 256) {
      int n = b;
      BtI[n * 256 + t] = __float2bfloat16(inp_w[t * 256 + n]);
    } else if (b < 768) {
      int n = b - 256;
      float v = 0.f;
      if (n < 288) v = off_w[t * 288 + n];
      else if (n < 432) v = mask_w[t * 144 + (n - 288)];
      BtOM[n * 256 + t] = __float2bfloat16(v);
      if (b == 256) {
        for (int idx = t; idx < 512; idx += 256) {
          float bv = (idx < 288) ? off_b[idx] : ((idx < 432) ? mask_b[idx - 288] : 0.f);
          bOM[idx] = bv;
        }
      }
    } else {
      int n = b - 768;
      BtO[n * 256 + t] = __float2bfloat16(out_w[t * 256 + n]);
    }
    return;
  }
  const int i = b - 1024;                 // 0..2047
  const int hw0 = (i & 63) * 64, c0 = ((i >> 6) & 7) * 32, n4 = i >> 9;
  #pragma unroll
  for (int r = 0; r < 8; ++r) {
    int idx = t + r * 256;
    int cl = idx >> 6, wl = idx & 63;
    tile[cl][wl] = x[(size_t)n4 * 1048576 + (size_t)(c0 + cl) * 4096 + hw0 + wl];
  }
  __syncthreads();
  #pragma unroll
  for (int r = 0; r < 2; ++r) {
    int idx = t + r * 256;                // 512 tasks = 64 pix * 8 cquads
    int pixl = idx >> 3, cq = idx & 7;
    unsigned short b0 = f2bf(tile[cq * 4 + 0][pixl]);
    unsigned short b1 = f2bf(tile[cq * 4 + 1][pixl]);
    unsigned short b2 = f2bf(tile[cq * 4 + 2][pixl]);
    unsigned short b3 = f2bf(tile[cq * 4 + 3][pixl]);
    uint2 u;
    u.x = (unsigned)b0 | ((unsigned)b1 << 16);
    u.y = (unsigned)b2 | ((unsigned)b3 << 16);
    *(uint2*)&xT[((size_t)n4 * 4096 + hw0 + pixl) * 256 + c0 + cq * 4] = u;
  }
}

// ---------------- 64x64 MFMA GEMM core --------------------------------------
struct G64 {
  f32x4 acc[2][2];
  int lane, quad, lr, wm, wn;
};

static __device__ inline void g64_loop(
    G64& g, const __hip_bfloat16* __restrict__ A,
    const __hip_bfloat16* __restrict__ Bt, size_t m0, int n0,
    short* As, short* Bs, int t)
{
  #pragma unroll
  for (int i = 0; i < 2; ++i)
    #pragma unroll
    for (int j = 0; j < 2; ++j)
      g.acc[i][j] = (f32x4){0.f, 0.f, 0.f, 0.f};
  const int row = t >> 2, kq = t & 3;
  for (int kt = 0; kt < 256; kt += 32) {
    g2lds16(A + (m0 + row) * 256 + kt + kq * 8, (char*)As + t * 16);
    g2lds16(Bt + (size_t)(n0 + row) * 256 + kt + kq * 8, (char*)Bs + t * 16);
    __syncthreads();
    bf16x8 bfv[2];
    #pragma unroll
    for (int ni = 0; ni < 2; ++ni)
      bfv[ni] = *(const bf16x8*)&Bs[(g.wn * 32 + ni * 16 + g.lr) * 32 + g.quad * 8];
    #pragma unroll
    for (int mi = 0; mi < 2; ++mi) {
      bf16x8 af = *(const bf16x8*)&As[(g.wm * 32 + mi * 16 + g.lr) * 32 + g.quad * 8];
      #pragma unroll
      for (int ni = 0; ni < 2; ++ni)
        g.acc[mi][ni] = __builtin_amdgcn_mfma_f32_16x16x32_bf16(af, bfv[ni], g.acc[mi][ni], 0, 0, 0);
    }
    __syncthreads();
  }
}

// ---------------- K2: stage2 (dwconv+LN+GELU+OM GEMM) ∥ input-proj GEMM -----
// blocks 0..255  : stage2, one image row (64 px), 16 waves, XCD-swizzled
// blocks 256..511: gemm_i, 4 independent 64x64 tiles (one per 256-thread sub-block)
__global__ __launch_bounds__(1024) void stage2_gi_k(
    const __hip_bfloat16* __restrict__ xT,
    const float* __restrict__ dw_w, const float* __restrict__ dw_b,
    const float* __restrict__ ln_g, const float* __restrict__ ln_b,
    const __hip_bfloat16* __restrict__ BtOM, const float* __restrict__ bOM,
    __hip_bfloat16* __restrict__ om,
    const __hip_bfloat16* __restrict__ BtI, const float* __restrict__ inp_b,
    __hip_bfloat16* __restrict__ xpu)
{
  __shared__ __align__(16) char smem[62464];
  const int bid = blockIdx.x;

  if (bid >= 256) {
    // -------- input-proj GEMM role: xT @ BtI -> xpu (bf16) --------
    const int sb = threadIdx.x >> 8;         // sub-block 0..3
    const int t = threadIdx.x & 255;
    const int tile = (bid - 256) * 4 + sb;   // 0..1023
    const int n0 = (tile & 3) * 64;
    const size_t m0 = (size_t)(tile >> 2) * 64;
    short* As = (short*)(smem + sb * 8192);
    short* Bs = (short*)(smem + sb * 8192 + 4096);

    G64 g;
    g.lane = t & 63; g.quad = g.lane >> 4; g.lr = g.lane & 15;
    int wave = t >> 6;
    g.wm = wave >> 1; g.wn = wave & 1;
    g64_loop(g, xT, BtI, m0, n0, As, Bs, t);

    #pragma unroll
    for (int mi = 0; mi < 2; ++mi) {
      #pragma unroll
      for (int ni = 0; ni < 2; ++ni) {
        int col = n0 + g.wn * 32 + ni * 16 + g.lr;
        float bv = inp_b[col];
        #pragma unroll
        for (int reg = 0; reg < 4; ++reg) {
          size_t m = m0 + g.wm * 32 + mi * 16 + g.quad * 4 + reg;
          xpu[m * 256 + col] = __float2bfloat16(g.acc[mi][ni][reg] + bv);
        }
      }
    }
    return;
  }

  // -------- stage2 role --------
  unsigned short* x1t = (unsigned short*)smem;                 // [64][264] 33792 B (persistent)
  unsigned short* xs  = (unsigned short*)(smem + 33792);       // [3][64][40] 15360 B
  float* wgt  = (float*)(smem + 33792 + 15360);                // [9][32] 1152 B
  float* psq  = (float*)(smem + 33792 + 15360 + 1152);         // ps[16*64]|pq[16*64] 8192 B
  float* murs = (float*)(smem + 33792 + 15360 + 1152 + 8192);  // mu[64]|rs[64] 512 B
  short* Bs   = (short*)(smem + 33792);                        // GEMM phase: [448][32] 28672 B

  const int blk = ((bid & 7) << 5) | (bid >> 3);               // bijective XCD swizzle
  const int n4 = blk >> 6, h = blk & 63;
  const int t = threadIdx.x;
  const int w = t & 63, q = t >> 6;          // pixel w, channel-group q (0..15)

  float s1 = 0.f, s2 = 0.f;
  for (int chunk = 0; chunk < 8; ++chunk) {
    const int ch0 = chunk * 32;
    if (t < 768) {                           // stage xs: 3 rows x 64 px x 32 ch
      int r = t >> 8, i = t & 255;
      int px = i >> 2, cq = i & 3;
      int hh = h + r - 1;
      uint4 v = {0, 0, 0, 0};
      if ((unsigned)hh < 64u)
        v = *(const uint4*)(xT + ((size_t)n4 * 4096 + (size_t)hh * 64 + px) * 256 + ch0 + cq * 8);
      *(uint4*)&xs[(r * 64 + px) * 40 + cq * 8] = v;
    }
    if (t < 288) {                           // stage weights [p][lc]
      int p = t >> 5, lc = t & 31;
      wgt[p * 32 + lc] = dw_w[(ch0 + lc) * 9 + p];
    }
    __syncthreads();
    {                                        // conv: 2 channels per thread
      int c = ch0 + 2 * q;
      float a0 = dw_b[c], a1 = dw_b[c + 1];
      #pragma unroll
      for (int p = 0; p < 9; ++p) {
        int dh = p / 3, dwd = p % 3 - 1;
        int ww = w + dwd;
        if ((unsigned)ww < 64u) {
          unsigned xv = *(const unsigned*)&xs[(dh * 64 + ww) * 40 + 2 * q];
          float wa = wgt[p * 32 + 2 * q], wb = wgt[p * 32 + 2 * q + 1];
          a0 = fmaf(us2f((unsigned short)(xv & 0xffff)), wa, a0);
          a1 = fmaf(us2f((unsigned short)(xv >> 16)), wb, a1);
        }
      }
      s1 += a0 + a1;
      s2 = fmaf(a0, a0, fmaf(a1, a1, s2));
      unsigned pk = (unsigned)f2bf(a0) | ((unsigned)f2bf(a1) << 16);
      *(unsigned*)&x1t[w * 264 + c] = pk;
    }
    __syncthreads();                         // before next chunk overwrites xs
  }

  psq[q * 64 + w] = s1;
  psq[1024 + q * 64 + w] = s2;
  __syncthreads();
  if (t < 64) {
    float a = 0.f, b = 0.f;
    #pragma unroll
    for (int j = 0; j < 16; ++j) { a += psq[j * 64 + t]; b += psq[1024 + j * 64 + t]; }
    float mu = a * (1.f / 256.f);
    murs[t] = mu;
    murs[64 + t] = rsqrtf(b * (1.f / 256.f) - mu * mu + 1e-5f);
  }
  __syncthreads();
  {                                          // normalize + GELU in place
    float mu = murs[w], rs = murs[64 + w];
    #pragma unroll
    for (int chunk = 0; chunk < 8; ++chunk) {
      int c = chunk * 32 + 2 * q;
      unsigned pk = *(const unsigned*)&x1t[w * 264 + c];
      float v0 = us2f((unsigned short)(pk & 0xffff));
      float v1 = us2f((unsigned short)(pk >> 16));
      float y0 = fmaf((v0 - mu) * rs, ln_g[c], ln_b[c]);
      float y1 = fmaf((v1 - mu) * rs, ln_g[c + 1], ln_b[c + 1]);
      float g0 = 0.5f * y0 * (1.f + erff(y0 * 0.70710678f));
      float g1 = 0.5f * y1 * (1.f + erff(y1 * 0.70710678f));
      *(unsigned*)&x1t[w * 264 + c] = (unsigned)f2bf(g0) | ((unsigned)f2bf(g1) << 16);
    }
  }
  __syncthreads();

  // OM GEMM: M=64 (pixels), N=448 (432 valid), K=256. 16 waves = 4m x 4n.
  const int wave = t >> 6, lane = t & 63;
  const int quad = lane >> 4, lr = lane & 15;
  const int wm = wave >> 2, wn = wave & 3;
  f32x4 acc[7];
  #pragma unroll
  for (int i = 0; i < 7; ++i) acc[i] = (f32x4){0.f, 0.f, 0.f, 0.f};

  for (int kt = 0; kt < 256; kt += 32) {
    __syncthreads();                         // Bs reads from prev iter done
    {
      int col = t >> 2, kq = t & 3;
      g2lds16(BtOM + (size_t)col * 256 + kt + kq * 8, (char*)Bs + t * 16);
      int j = t + 1024;
      if (j < 1792) {
        col = j >> 2; kq = j & 3;
        g2lds16(BtOM + (size_t)col * 256 + kt + kq * 8, (char*)Bs + j * 16);
      }
    }
    __syncthreads();
    bf16x8 af = *(const bf16x8*)&x1t[(wm * 16 + lr) * 264 + kt + quad * 8];
    #pragma unroll
    for (int ni = 0; ni < 7; ++ni) {
      bf16x8 bf = *(const bf16x8*)&Bs[(wn * 112 + ni * 16 + lr) * 32 + quad * 8];
      acc[ni] = __builtin_amdgcn_mfma_f32_16x16x32_bf16(af, bf, acc[ni], 0, 0, 0);
    }
  }

  const size_t pix0 = (size_t)n4 * 4096 + (size_t)h * 64;
  #pragma unroll
  for (int ni = 0; ni < 7; ++ni) {
    int col = wn * 112 + ni * 16 + lr;
    if (col < 432) {
      float bv = bOM[col];
      #pragma unroll
      for (int reg = 0; reg < 4; ++reg) {
        int m = wm * 16 + quad * 4 + reg;
        om[(pix0 + m) * 448 + col] = __float2bfloat16(acc[ni][reg] + bv);
      }
    }
  }
}

// ---------------- K3: sampling -> LDS tile -> output-proj GEMM -> fp32 NCHW -
// block = 64 pixels (one image row), 1024 threads. samp tile never hits global.
__global__ __launch_bounds__(1024) void fused_so_k(
    const __hip_bfloat16* __restrict__ xpu, const __hip_bfloat16* __restrict__ om,
    const __hip_bfloat16* __restrict__ BtO, const float* __restrict__ out_b,
    float* __restrict__ out)
{
  __shared__ __align__(16) char smem[50176];
  unsigned short* st = (unsigned short*)smem;          // samp tile [64][264] 33792 B
  short* Bs = (short*)(smem + 33792);                  // B-stage [256][32] 16384 B

  const int bid = blockIdx.x;                          // 256
  const int swz = ((bid & 7) << 5) | (bid >> 3);       // bijective XCD swizzle
  const int pix0 = swz << 6;                           // 64 consecutive pixels
  const int t = threadIdx.x;

  // ---- sampling phase: thread = (pixel pl, group g) ----
  {
    const int pl = t >> 4, g = t & 15;
    const int pix = pix0 + pl;
    const int n4s = pix >> 12;
    const int hw = pix & 4095;
    const int h = hw >> 6, w = hw & 63;
    const unsigned short* omp = (const unsigned short*)om + (size_t)pix * 448;

    float mk[9];
    {
      float mx = -1e30f;
      #pragma unroll
      for (int p = 0; p < 9; ++p) { mk[p] = us2f(omp[288 + g * 9 + p]); mx = fmaxf(mx, mk[p]); }
      float se = 0.f;
      #pragma unroll
      for (int p = 0; p < 9; ++p) { mk[p] = __expf(mk[p] - mx); se += mk[p]; }
      float inv = 1.f / se;
      #pragma unroll
      for (int p = 0; p < 9; ++p) mk[p] *= inv;
    }

    const __hip_bfloat16* xpg = xpu + (g << 4);
    float ax[16];
    #pragma unroll
    for (int i = 0; i < 16; ++i) ax[i] = 0.f;

    auto corner = [&](int iy, int ix, float wt) {
      if ((unsigned)(iy - 1) >= 64u || (unsigned)(ix - 1) >= 64u) return;
      const __hip_bfloat16* src =
          xpg + ((size_t)((n4s << 12) + (iy - 1) * 64 + (ix - 1)) << 8);
      uint4 u0 = *(const uint4*)src;
      uint4 u1 = *(const uint4*)(src + 8);
      const unsigned uu[8] = {u0.x, u0.y, u0.z, u0.w, u1.x, u1.y, u1.z, u1.w};
      #pragma unroll
      for (int i = 0; i < 8; ++i) {
        float lo = us2f((unsigned short)(uu[i] & 0xffff));
        float hi = us2f((unsigned short)(uu[i] >> 16));
        ax[2 * i + 0] = fmaf(wt, lo, ax[2 * i + 0]);
        ax[2 * i + 1] = fmaf(wt, hi, ax[2 * i + 1]);
      }
    };

    #pragma unroll
    for (int p = 0; p < 9; ++p) {
      float ox = us2f(omp[g * 18 + 2 * p]), oy = us2f(omp[g * 18 + 2 * p + 1]);
      float px = (float)(w + p / 3) + ox;
      float py = (float)(h + p % 3) + oy;
      float xf = floorf(px), yf = floorf(py);
      float wx = px - xf, wy = py - yf;
      int ix = (int)xf, iy = (int)yf;
      float m = mk[p];
      corner(iy,     ix,     (1.f - wy) * (1.f - wx) * m);
      corner(iy,     ix + 1, (1.f - wy) * wx * m);
      corner(iy + 1, ix,     wy * (1.f - wx) * m);
      corner(iy + 1, ix + 1, wy * wx * m);
    }

    unsigned short ub[16];
    #pragma unroll
    for (int i = 0; i < 16; ++i) ub[i] = f2bf(ax[i]);
    uint4 u0, u1;
    u0.x = (unsigned)ub[0] | ((unsigned)ub[1] << 16);
    u0.y = (unsigned)ub[2] | ((unsigned)ub[3] << 16);
    u0.z = (unsigned)ub[4] | ((unsigned)ub[5] << 16);
    u0.w = (unsigned)ub[6] | ((unsigned)ub[7] << 16);
    u1.x = (unsigned)ub[8] | ((unsigned)ub[9] << 16);
    u1.y = (unsigned)ub[10] | ((unsigned)ub[11] << 16);
    u1.z = (unsigned)ub[12] | ((unsigned)ub[13] << 16);
    u1.w = (unsigned)ub[14] | ((unsigned)ub[15] << 16);
    *(uint4*)&st[pl * 264 + g * 16] = u0;
    *(uint4*)&st[pl * 264 + g * 16 + 8] = u1;
  }

  // ---- output-proj GEMM: st(64x256) @ BtO^T -> out, 16 waves = 4m x 4n ----
  const int wave = t >> 6, lane = t & 63;
  const int quad = lane >> 4, lr = lane & 15;
  const int wm = wave >> 2, wn = wave & 3;
  f32x4 acc[4];
  #pragma unroll
  for (int i = 0; i < 4; ++i) acc[i] = (f32x4){0.f, 0.f, 0.f, 0.f};

  for (int kt = 0; kt < 256; kt += 32) {
    __syncthreads();                         // st writes done / prev Bs reads done
    {
      int col = t >> 2, kq = t & 3;          // 256 cols x 32 k
      g2lds16(BtO + (size_t)col * 256 + kt + kq * 8, (char*)Bs + t * 16);
    }
    __syncthreads();
    bf16x8 af = *(const bf16x8*)&st[(wm * 16 + lr) * 264 + kt + quad * 8];
    #pragma unroll
    for (int ni = 0; ni < 4; ++ni) {
      bf16x8 bf = *(const bf16x8*)&Bs[(wn * 64 + ni * 16 + lr) * 32 + quad * 8];
      acc[ni] = __builtin_amdgcn_mfma_f32_16x16x32_bf16(af, bf, acc[ni], 0, 0, 0);
    }
  }

  // direct fp32 NCHW stores: each 64B line fully covered by one wave
  const int n4 = pix0 >> 12, hw0 = pix0 & 4095;
  #pragma unroll
  for (int ni = 0; ni < 4; ++ni) {
    int col = wn * 64 + ni * 16 + lr;
    float bv = out_b[col];
    float4 v;
    v.x = acc[ni][0] + bv; v.y = acc[ni][1] + bv;
    v.z = acc[ni][2] + bv; v.w = acc[ni][3] + bv;
    *(float4*)&out[(size_t)(n4 * 256 + col) * 4096 + hw0 + wm * 16 + quad * 4] = v;
  }
}

extern "C" void kernel_launch(void* const* d_in, const int* in_sizes, int n_in,
                              void* d_out, int out_size, void* d_ws, size_t ws_size,
                              hipStream_t stream) {
  const float* x      = (const float*)d_in[0];
  const float* dw_w   = (const float*)d_in[1];
  const float* dw_b   = (const float*)d_in[2];
  const float* ln_g   = (const float*)d_in[3];
  const float* ln_b   = (const float*)d_in[4];
  const float* off_w  = (const float*)d_in[5];
  const float* off_b  = (const float*)d_in[6];
  const float* mask_w = (const float*)d_in[7];
  const float* mask_b = (const float*)d_in[8];
  const float* inp_w  = (const float*)d_in[9];
  const float* inp_b  = (const float*)d_in[10];
  const float* out_w  = (const float*)d_in[11];
  const float* out_b  = (const float*)d_in[12];
  float* out = (float*)d_out;

  char* w0 = (char*)d_ws;
  __hip_bfloat16* xpu  = (__hip_bfloat16*)(w0);               //  8,388,608 B
  __hip_bfloat16* xT   = (__hip_bfloat16*)(w0 + 8388608);     //  8,388,608 B
  __hip_bfloat16* om   = (__hip_bfloat16*)(w0 + 16777216);    // 14,680,064 B
  __hip_bfloat16* BtI  = (__hip_bfloat16*)(w0 + 31457280);    //    131,072 B
  __hip_bfloat16* BtOM = (__hip_bfloat16*)(w0 + 31588352);    //    262,144 B
  __hip_bfloat16* BtO  = (__hip_bfloat16*)(w0 + 31850496);    //    131,072 B
  float*          bOM  = (float*)(w0 + 31981568);             //      2,048 B
  if (ws_size < 31983616) return;

  prep_xt_k<<<3072, 256, 0, stream>>>(x, inp_w, off_w, off_b, mask_w, mask_b,
                                      out_w, BtI, BtOM, BtO, bOM, xT);
  stage2_gi_k<<<512, 1024, 0, stream>>>(xT, dw_w, dw_b, ln_g, ln_b, BtOM, bOM, om,
                                        BtI, inp_b, xpu);
  fused_so_k<<<256, 1024, 0, stream>>>(xpu, om, BtO, out_b, out);
}